// Round 2
// baseline (175.273 us; speedup 1.0000x reference)
//
#include <hip/hip_runtime.h>

// Problem constants (fixed by setup_inputs):
//   x: (64, 8192) f32   weight: (8192, 2048) f32
//   random_numbers: (4,) int (int32 or int64 layout, values in [1, 2^20))
//   y: (64, 8192) f32
#define K_FULL   8192
#define M_ROWS   64
#define N_OUT    8192
#define N_COMP   2048
#define P_MERS   2147483647

// ws layout:
//   [0, 512KB)        : xcT[N_COMP][M_ROWS] f32  (transposed compressed x)
//   [512KB, 544KB)    : colidx[K_FULL] int32
#define XCT_ELEMS (N_COMP * M_ROWS)

__global__ void k_init(float* __restrict__ xcT, int* __restrict__ colidx,
                       const int* __restrict__ rn_raw) {
    int tid = blockIdx.x * blockDim.x + threadIdx.x;
    if (tid < XCT_ELEMS) xcT[tid] = 0.0f;
    if (tid < K_FULL) {
        int col;
        if (rn_raw[1] == 0 && rn_raw[3] == 0) {
            // int64 storage => JAX x64 enabled => exact int64 hash.
            long long r0 = (long long)rn_raw[0];
            long long r1 = (long long)rn_raw[2];
            long long h = (r0 * (long long)tid + r1) % (long long)P_MERS;
            col = (int)(h % (long long)N_COMP);
        } else {
            // int32 storage => JAX x64 disabled => reference computed
            // r0*j+r1 in int32 with wraparound, then floored mod P mod 2048.
            unsigned int t = (unsigned int)rn_raw[0] * (unsigned int)tid
                           + (unsigned int)rn_raw[1];
            int ti = (int)t;  // int32 wraparound value
            int m1 = ti % P_MERS;            // C truncated mod
            if (m1 < 0) m1 += P_MERS;        // -> floored (nonneg) mod
            col = m1 & (N_COMP - 1);         // m1 >= 0, so & == floored mod
        }
        colidx[tid] = col;
    }
}

// Scatter-reduce: xcT[c][m] += x[m][j] for c = colidx[j].
// tid = m*8192 + j -> coalesced x and colidx reads.
__global__ void k_scatter(const float* __restrict__ x,
                          const int* __restrict__ colidx,
                          float* __restrict__ xcT) {
    int tid = blockIdx.x * blockDim.x + threadIdx.x;  // < 64*8192
    int j = tid & (K_FULL - 1);
    int m = tid >> 13;
    float v = x[tid];
    int c = colidx[j];
    atomicAdd(&xcT[c * M_ROWS + m], v);
}

// Skinny GEMM: y[m][n] = sum_c xcT[c][m] * W[n][c]
// 256 blocks x 256 threads. Block covers BN=32 output cols (8 per wave).
// lane = m (wave64 covers all 64 rows). xcT staged in LDS per K-chunk.
#define BN 32
#define NN 8
#define KC 128

__global__ __launch_bounds__(256) void k_gemm(const float* __restrict__ W,
                                              const float* __restrict__ xcT,
                                              float* __restrict__ y) {
    __shared__ float xs[KC * M_ROWS];  // 32 KB, also reused for epilogue
    const int lane = threadIdx.x & 63;
    const int wave = __builtin_amdgcn_readfirstlane((int)(threadIdx.x >> 6));
    const int n0 = blockIdx.x * BN + wave * NN;

    float acc[NN];
#pragma unroll
    for (int n = 0; n < NN; ++n) acc[n] = 0.0f;

    for (int kc = 0; kc < N_COMP; kc += KC) {
        __syncthreads();  // protect LDS reuse from previous iteration
        // Stage xcT[kc..kc+KC)[0..64) : KC*64 floats = 2048 float4, 8 per thread
        const float4* src = (const float4*)(xcT + kc * M_ROWS);
        float4* dst = (float4*)xs;
#pragma unroll
        for (int i = 0; i < 8; ++i)
            dst[threadIdx.x + 256 * i] = src[threadIdx.x + 256 * i];
        __syncthreads();

        for (int k = 0; k < KC; k += 4) {
            float xv[4];
#pragma unroll
            for (int q = 0; q < 4; ++q) xv[q] = xs[(k + q) * M_ROWS + lane];
            float4 wv[NN];
#pragma unroll
            for (int n = 0; n < NN; ++n)
                wv[n] = *(const float4*)(W + (size_t)(n0 + n) * N_COMP + kc + k);
#pragma unroll
            for (int n = 0; n < NN; ++n) {
                acc[n] = fmaf(xv[0], wv[n].x, acc[n]);
                acc[n] = fmaf(xv[1], wv[n].y, acc[n]);
                acc[n] = fmaf(xv[2], wv[n].z, acc[n]);
                acc[n] = fmaf(xv[3], wv[n].w, acc[n]);
            }
        }
    }

    // Epilogue: LDS transpose for coalesced stores.
    __syncthreads();
    float* ys = xs;  // [64][BN] f32 = 8 KB
#pragma unroll
    for (int n = 0; n < NN; ++n)
        ys[lane * BN + wave * NN + n] = acc[n];
    __syncthreads();
    // 64*32 = 512 float4, 2 per thread; f = m*8 + c4
    const float4* s4 = (const float4*)ys;
#pragma unroll
    for (int i = 0; i < 2; ++i) {
        int f = threadIdx.x + 256 * i;
        int m = f >> 3;
        int c4 = f & 7;
        *(float4*)(y + (size_t)m * N_OUT + blockIdx.x * BN + c4 * 4) = s4[f];
    }
}

extern "C" void kernel_launch(void* const* d_in, const int* in_sizes, int n_in,
                              void* d_out, int out_size, void* d_ws, size_t ws_size,
                              hipStream_t stream) {
    const float* x = (const float*)d_in[0];
    const float* W = (const float*)d_in[1];
    const int* rn = (const int*)d_in[2];
    float* y = (float*)d_out;

    float* xcT = (float*)d_ws;
    int* colidx = (int*)((char*)d_ws + XCT_ELEMS * sizeof(float));

    // 1) zero xcT + compute colidx
    k_init<<<(XCT_ELEMS + 255) / 256, 256, 0, stream>>>(xcT, colidx, rn);
    // 2) scatter-reduce x -> xcT
    k_scatter<<<(M_ROWS * K_FULL) / 256, 256, 0, stream>>>(x, colidx, xcT);
    // 3) GEMM y = xc @ W^T
    k_gemm<<<N_OUT / BN, 256, 0, stream>>>(W, xcT, y);
}

// Round 3
// 64.244 us; speedup vs baseline: 2.7283x; 2.7283x over previous
//
#include <hip/hip_runtime.h>

// Problem constants (fixed by setup_inputs):
//   x: (64, 8192) f32   weight: (8192, 2048) f32
//   random_numbers: (4,) int (int32 or int64 storage, values in [1, 2^20))
//   y: (64, 8192) f32
#define K_FULL   8192
#define M_ROWS   64
#define N_OUT    8192
#define N_COMP   2048
#define P_MERS   2147483647

#define XCT_ELEMS (N_COMP * M_ROWS)

// ws layout:
//   [0, 512KB)      : xcT f32 [N_COMP][M_ROWS]  (scatter target, atomics)
//   [512KB, 768KB)  : xcB bf16 [M_ROWS][N_COMP] (packed GEMM A operand)

typedef __attribute__((ext_vector_type(8))) short bf16x8;
typedef __attribute__((ext_vector_type(4))) float f32x4;

__device__ __forceinline__ unsigned short f2bf(float f) {
    // round-to-nearest-even f32 -> bf16 (finite values)
    unsigned int u = __float_as_uint(f);
    unsigned int r = (u + 0x7FFFu + ((u >> 16) & 1u)) >> 16;
    return (unsigned short)r;
}

__device__ __forceinline__ int hash_col(int j, const int* __restrict__ rn) {
    if (rn[1] == 0 && rn[3] == 0) {
        // int64 storage (JAX x64 on): exact int64 hash
        long long r0 = (long long)rn[0];
        long long r1 = (long long)rn[2];
        long long h = (r0 * (long long)j + r1) % (long long)P_MERS;
        return (int)(h % (long long)N_COMP);
    } else {
        // int32 storage (JAX x64 off): int32 wraparound + floored mod
        unsigned int t = (unsigned int)rn[0] * (unsigned int)j + (unsigned int)rn[1];
        int ti = (int)t;
        int m1 = ti % P_MERS;
        if (m1 < 0) m1 += P_MERS;
        return m1 & (N_COMP - 1);
    }
}

// Scatter-reduce: xcT[c][m] += x[m][j] for c = h(j). Hash inlined (uniform per wave-row).
__global__ void k_scatter(const float* __restrict__ x, const int* __restrict__ rn,
                          float* __restrict__ xcT) {
    int tid = blockIdx.x * blockDim.x + threadIdx.x;  // < 64*8192
    int j = tid & (K_FULL - 1);
    int c = hash_col(j, rn);
    atomicAdd(&xcT[c * M_ROWS + (tid >> 13)], x[tid]);
}

// Pack: xcT f32 [c][m] -> xcB bf16 [m][c]
__global__ void k_pack(const float* __restrict__ xcT, unsigned short* __restrict__ xcB) {
    int tid = blockIdx.x * blockDim.x + threadIdx.x;  // < 131072
    int c = tid >> 6;
    int m = tid & 63;
    xcB[(size_t)m * N_COMP + c] = f2bf(xcT[tid]);
}

// MFMA GEMM: y[m][n] = sum_c xc[m][c] * W[n][c]
// Grid: 512 blocks x 256 threads (4 waves). Block owns 16 output columns (n).
// Wave w computes the partial sum over k-slice [w*512, (w+1)*512); in-block
// LDS reduce at the end (deterministic). A-fragments read directly from the
// L2-resident xcB (256 KB); W streams from HBM, converted f32->bf16 in-register.
#define KSLICES 4
#define KSL     (N_COMP / KSLICES)   // 512
#define KSTEPS  (KSL / 32)           // 16

__global__ __launch_bounds__(256) void k_gemm(const float* __restrict__ W,
                                              const unsigned short* __restrict__ xcB,
                                              float* __restrict__ y) {
    __shared__ float ys[KSLICES][M_ROWS][16];  // 16 KB
    const int tid  = threadIdx.x;
    const int lane = tid & 63;
    const int w    = __builtin_amdgcn_readfirstlane(tid >> 6);  // k-slice id
    const int nr   = lane & 15;   // fragment row/col index (A-row m, B-col n)
    const int kg   = lane >> 4;   // k-group 0..3 (8 k each)
    const int n0   = blockIdx.x * 16;

    const float*          wp  = W   + (size_t)(n0 + nr) * N_COMP + w * KSL + kg * 8;
    const unsigned short* ap  = xcB + (size_t)nr * N_COMP        + w * KSL + kg * 8;

    f32x4 acc0 = {0.f, 0.f, 0.f, 0.f};
    f32x4 acc1 = {0.f, 0.f, 0.f, 0.f};
    f32x4 acc2 = {0.f, 0.f, 0.f, 0.f};
    f32x4 acc3 = {0.f, 0.f, 0.f, 0.f};

#pragma unroll
    for (int s = 0; s < KSTEPS; ++s) {
        const int ko = s * 32;
        // B fragment: 8 consecutive k of W row (n0+nr), f32 -> bf16
        float4 w0 = *(const float4*)(wp + ko);
        float4 w1 = *(const float4*)(wp + ko + 4);
        bf16x8 b;
        b[0] = (short)f2bf(w0.x); b[1] = (short)f2bf(w0.y);
        b[2] = (short)f2bf(w0.z); b[3] = (short)f2bf(w0.w);
        b[4] = (short)f2bf(w1.x); b[5] = (short)f2bf(w1.y);
        b[6] = (short)f2bf(w1.z); b[7] = (short)f2bf(w1.w);
        // A fragments: rows nr, nr+16, nr+32, nr+48 of xcB, same k range
        bf16x8 a0 = *(const bf16x8*)(ap + ko);
        bf16x8 a1 = *(const bf16x8*)(ap + 16 * N_COMP + ko);
        bf16x8 a2 = *(const bf16x8*)(ap + 32 * N_COMP + ko);
        bf16x8 a3 = *(const bf16x8*)(ap + 48 * N_COMP + ko);
        acc0 = __builtin_amdgcn_mfma_f32_16x16x32_bf16(a0, b, acc0, 0, 0, 0);
        acc1 = __builtin_amdgcn_mfma_f32_16x16x32_bf16(a1, b, acc1, 0, 0, 0);
        acc2 = __builtin_amdgcn_mfma_f32_16x16x32_bf16(a2, b, acc2, 0, 0, 0);
        acc3 = __builtin_amdgcn_mfma_f32_16x16x32_bf16(a3, b, acc3, 0, 0, 0);
    }

    // C/D layout (m89-verified): col = lane&15, row = (lane>>4)*4 + j
#pragma unroll
    for (int j = 0; j < 4; ++j) {
        ys[w][ 0 + kg * 4 + j][nr] = acc0[j];
        ys[w][16 + kg * 4 + j][nr] = acc1[j];
        ys[w][32 + kg * 4 + j][nr] = acc2[j];
        ys[w][48 + kg * 4 + j][nr] = acc3[j];
    }
    __syncthreads();

    // Reduce k-slices and store: 1024 outputs, 4 per thread
#pragma unroll
    for (int i = 0; i < 4; ++i) {
        int o = tid + 256 * i;
        int m = o >> 4;
        int n = o & 15;
        float s = ys[0][m][n] + ys[1][m][n] + ys[2][m][n] + ys[3][m][n];
        y[(size_t)m * N_OUT + n0 + n] = s;
    }
}

extern "C" void kernel_launch(void* const* d_in, const int* in_sizes, int n_in,
                              void* d_out, int out_size, void* d_ws, size_t ws_size,
                              hipStream_t stream) {
    const float* x = (const float*)d_in[0];
    const float* W = (const float*)d_in[1];
    const int* rn  = (const int*)d_in[2];
    float* y       = (float*)d_out;

    float* xcT          = (float*)d_ws;
    unsigned short* xcB = (unsigned short*)((char*)d_ws + XCT_ELEMS * sizeof(float));

    hipMemsetAsync(xcT, 0, XCT_ELEMS * sizeof(float), stream);
    k_scatter<<<(M_ROWS * K_FULL) / 256, 256, 0, stream>>>(x, rn, xcT);
    k_pack<<<XCT_ELEMS / 256, 256, 0, stream>>>(xcT, xcB);
    k_gemm<<<N_OUT / 16, 256, 0, stream>>>(W, xcB, y);
}

// Round 4
// 41.263 us; speedup vs baseline: 4.2477x; 1.5569x over previous
//
#include <hip/hip_runtime.h>

// Problem constants (fixed by setup_inputs):
//   x: (64, 8192) f32   weight: (8192, 2048) f32
//   random_numbers: (4,) int (int32 or int64 storage, values in [1, 2^20))
//   y: (64, 8192) f32
#define K_FULL   8192
#define M_ROWS   64
#define N_OUT    8192
#define N_COMP   2048
#define P_MERS   2147483647

// ws layout: [0, 256KB) : xcB bf16 [M_ROWS][N_COMP] (GEMM A operand)

typedef __attribute__((ext_vector_type(8))) short bf16x8;
typedef __attribute__((ext_vector_type(4))) float f32x4;

__device__ __forceinline__ unsigned short f2bf(float f) {
    // round-to-nearest-even f32 -> bf16 (finite values)
    unsigned int u = __float_as_uint(f);
    unsigned int r = (u + 0x7FFFu + ((u >> 16) & 1u)) >> 16;
    return (unsigned short)r;
}

__device__ __forceinline__ int hash_col(int j, int rn0, int rn1, int rn2, int rn3) {
    if (rn1 == 0 && rn3 == 0) {
        // int64 storage (JAX x64 on): exact int64 hash
        long long r0 = (long long)rn0;
        long long r1 = (long long)rn2;
        long long h = (r0 * (long long)j + r1) % (long long)P_MERS;
        return (int)(h % (long long)N_COMP);
    } else {
        // int32 storage (JAX x64 off): int32 wraparound + floored mod
        unsigned int t = (unsigned int)rn0 * (unsigned int)j + (unsigned int)rn1;
        int ti = (int)t;
        int m1 = ti % P_MERS;
        if (m1 < 0) m1 += P_MERS;
        return m1 & (N_COMP - 1);
    }
}

// Fused scatter+pack: per block (one m row), accumulate xc[m][*] in LDS via
// ds atomics, then pack to bf16 xcB[m][*]. No global zeroing, no global atomics.
__global__ __launch_bounds__(1024) void k_xc(const float* __restrict__ x,
                                             const int* __restrict__ rn,
                                             unsigned short* __restrict__ xcB) {
    __shared__ float row[N_COMP];
    const int m = blockIdx.x;
    const int tid = threadIdx.x;
    row[tid] = 0.0f;
    row[tid + 1024] = 0.0f;
    const int rn0 = rn[0], rn1 = rn[1], rn2 = rn[2], rn3 = rn[3];
    __syncthreads();

    const float* xm = x + (size_t)m * K_FULL;
#pragma unroll
    for (int it = 0; it < 2; ++it) {
        int j0 = (tid + it * 1024) * 4;
        float4 v = *(const float4*)(xm + j0);
        atomicAdd(&row[hash_col(j0 + 0, rn0, rn1, rn2, rn3)], v.x);
        atomicAdd(&row[hash_col(j0 + 1, rn0, rn1, rn2, rn3)], v.y);
        atomicAdd(&row[hash_col(j0 + 2, rn0, rn1, rn2, rn3)], v.z);
        atomicAdd(&row[hash_col(j0 + 3, rn0, rn1, rn2, rn3)], v.w);
    }
    __syncthreads();

    // pack 2 consecutive c per thread -> one dword store
    unsigned int p = (unsigned int)f2bf(row[2 * tid])
                   | ((unsigned int)f2bf(row[2 * tid + 1]) << 16);
    ((unsigned int*)(xcB + (size_t)m * N_COMP))[tid] = p;
}

// MFMA GEMM: y[m][n] = sum_c xc[m][c] * W[n][c]
// Grid: 512 blocks x 512 threads (8 waves). Block owns 16 output columns (n).
// Wave w computes the partial sum over k-slice [w*256, (w+1)*256); in-block
// LDS reduce at the end (deterministic). A-fragments read directly from the
// L2-resident xcB (256 KB); W streams from HBM, converted f32->bf16 in-register.
#define KSLICES 8
#define KSL     (N_COMP / KSLICES)   // 256
#define KSTEPS  (KSL / 32)           // 8

__global__ __launch_bounds__(512) void k_gemm(const float* __restrict__ W,
                                              const unsigned short* __restrict__ xcB,
                                              float* __restrict__ y) {
    __shared__ float ys[KSLICES][M_ROWS][16];  // 32 KB
    const int tid  = threadIdx.x;
    const int lane = tid & 63;
    const int w    = __builtin_amdgcn_readfirstlane(tid >> 6);  // k-slice id
    const int nr   = lane & 15;   // fragment row/col index (A-row m, B-col n)
    const int kg   = lane >> 4;   // k-group 0..3 (8 k each)
    const int n0   = blockIdx.x * 16;

    const float*          wp = W   + (size_t)(n0 + nr) * N_COMP + w * KSL + kg * 8;
    const unsigned short* ap = xcB + (size_t)nr * N_COMP        + w * KSL + kg * 8;

    f32x4 acc0 = {0.f, 0.f, 0.f, 0.f};
    f32x4 acc1 = {0.f, 0.f, 0.f, 0.f};
    f32x4 acc2 = {0.f, 0.f, 0.f, 0.f};
    f32x4 acc3 = {0.f, 0.f, 0.f, 0.f};

#pragma unroll
    for (int s = 0; s < KSTEPS; ++s) {
        const int ko = s * 32;
        float4 w0 = *(const float4*)(wp + ko);
        float4 w1 = *(const float4*)(wp + ko + 4);
        bf16x8 b;
        b[0] = (short)f2bf(w0.x); b[1] = (short)f2bf(w0.y);
        b[2] = (short)f2bf(w0.z); b[3] = (short)f2bf(w0.w);
        b[4] = (short)f2bf(w1.x); b[5] = (short)f2bf(w1.y);
        b[6] = (short)f2bf(w1.z); b[7] = (short)f2bf(w1.w);
        bf16x8 a0 = *(const bf16x8*)(ap + ko);
        bf16x8 a1 = *(const bf16x8*)(ap + 16 * N_COMP + ko);
        bf16x8 a2 = *(const bf16x8*)(ap + 32 * N_COMP + ko);
        bf16x8 a3 = *(const bf16x8*)(ap + 48 * N_COMP + ko);
        acc0 = __builtin_amdgcn_mfma_f32_16x16x32_bf16(a0, b, acc0, 0, 0, 0);
        acc1 = __builtin_amdgcn_mfma_f32_16x16x32_bf16(a1, b, acc1, 0, 0, 0);
        acc2 = __builtin_amdgcn_mfma_f32_16x16x32_bf16(a2, b, acc2, 0, 0, 0);
        acc3 = __builtin_amdgcn_mfma_f32_16x16x32_bf16(a3, b, acc3, 0, 0, 0);
    }

    // C/D layout (m89-verified): col = lane&15, row = (lane>>4)*4 + j
#pragma unroll
    for (int j = 0; j < 4; ++j) {
        ys[w][ 0 + kg * 4 + j][nr] = acc0[j];
        ys[w][16 + kg * 4 + j][nr] = acc1[j];
        ys[w][32 + kg * 4 + j][nr] = acc2[j];
        ys[w][48 + kg * 4 + j][nr] = acc3[j];
    }
    __syncthreads();

    // Reduce k-slices and store: 1024 outputs, 2 per thread
#pragma unroll
    for (int i = 0; i < 2; ++i) {
        int o = tid + 512 * i;
        int m = o >> 4;
        int n = o & 15;
        float s = 0.f;
#pragma unroll
        for (int q = 0; q < KSLICES; ++q) s += ys[q][m][n];
        y[(size_t)m * N_OUT + n0 + n] = s;
    }
}

extern "C" void kernel_launch(void* const* d_in, const int* in_sizes, int n_in,
                              void* d_out, int out_size, void* d_ws, size_t ws_size,
                              hipStream_t stream) {
    const float* x = (const float*)d_in[0];
    const float* W = (const float*)d_in[1];
    const int* rn  = (const int*)d_in[2];
    float* y       = (float*)d_out;

    unsigned short* xcB = (unsigned short*)d_ws;

    k_xc<<<M_ROWS, 1024, 0, stream>>>(x, rn, xcB);
    k_gemm<<<N_OUT / 16, 512, 0, stream>>>(W, xcB, y);
}

// Round 5
// 36.344 us; speedup vs baseline: 4.8226x; 1.1353x over previous
//
#include <hip/hip_runtime.h>

// Problem constants (fixed by setup_inputs):
//   x: (64, 8192) f32   weight: (8192, 2048) f32
//   random_numbers: (4,) int (int32 or int64 storage, values in [1, 2^20))
//   y: (64, 8192) f32
#define K_FULL   8192
#define M_ROWS   64
#define N_OUT    8192
#define N_COMP   2048
#define P_MERS   2147483647

// ws layout:
//   [0, 2MB)        : partial f32 [256][N_COMP]   (b = m*4 + jq)
//   [2MB, 2.25MB)   : xcB bf16 [M_ROWS][N_COMP]   (GEMM A operand)

typedef __attribute__((ext_vector_type(8))) short bf16x8;
typedef __attribute__((ext_vector_type(4))) float f32x4;

__device__ __forceinline__ unsigned short f2bf(float f) {
    unsigned int u = __float_as_uint(f);
    unsigned int r = (u + 0x7FFFu + ((u >> 16) & 1u)) >> 16;
    return (unsigned short)r;
}

__device__ __forceinline__ int hash_col(int j, int rn0, int rn1, int rn2, int rn3) {
    if (rn1 == 0 && rn3 == 0) {
        // int64 storage (JAX x64 on): exact int64 hash
        long long r0 = (long long)rn0;
        long long r1 = (long long)rn2;
        long long h = (r0 * (long long)j + r1) % (long long)P_MERS;
        return (int)(h % (long long)N_COMP);
    } else {
        // int32 storage (JAX x64 off): int32 wraparound + floored mod
        unsigned int t = (unsigned int)rn0 * (unsigned int)j + (unsigned int)rn1;
        int ti = (int)t;
        int m1 = ti % P_MERS;
        if (m1 < 0) m1 += P_MERS;
        return m1 & (N_COMP - 1);
    }
}

// Partial compressed rows: block b = (m, jq). Accumulate x[m][jq*2048 .. +2048)
// into LDS row by hashed column, then write partial[b][*]. No global atomics.
__global__ __launch_bounds__(512) void k_part(const float* __restrict__ x,
                                              const int* __restrict__ rn,
                                              float* __restrict__ partial) {
    __shared__ float row[N_COMP];
    const int b = blockIdx.x;
    const int m = b >> 2;
    const int jq = b & 3;
    const int tid = threadIdx.x;
#pragma unroll
    for (int i = 0; i < 4; ++i) row[tid + 512 * i] = 0.0f;
    const int rn0 = rn[0], rn1 = rn[1], rn2 = rn[2], rn3 = rn[3];
    __syncthreads();

    const int j0 = jq * 2048 + tid * 4;
    float4 v = *(const float4*)(x + (size_t)m * K_FULL + j0);
    atomicAdd(&row[hash_col(j0 + 0, rn0, rn1, rn2, rn3)], v.x);
    atomicAdd(&row[hash_col(j0 + 1, rn0, rn1, rn2, rn3)], v.y);
    atomicAdd(&row[hash_col(j0 + 2, rn0, rn1, rn2, rn3)], v.z);
    atomicAdd(&row[hash_col(j0 + 3, rn0, rn1, rn2, rn3)], v.w);
    __syncthreads();

    float4 o = { row[4 * tid], row[4 * tid + 1], row[4 * tid + 2], row[4 * tid + 3] };
    *(float4*)(partial + (size_t)b * N_COMP + 4 * tid) = o;
}

// Reduce 4 partials per (m, c) and pack to bf16 xcB[m][c].
__global__ __launch_bounds__(256) void k_pack(const float* __restrict__ partial,
                                              unsigned short* __restrict__ xcB) {
    const int b = blockIdx.x;          // 256 blocks
    const int m = b >> 2;
    const int c0 = (b & 3) * 512 + threadIdx.x * 2;
    const float* p = partial + (size_t)m * 4 * N_COMP + c0;
    float s0 = p[0] + p[N_COMP] + p[2 * N_COMP] + p[3 * N_COMP];
    float s1 = p[1] + p[N_COMP + 1] + p[2 * N_COMP + 1] + p[3 * N_COMP + 1];
    unsigned int pk = (unsigned int)f2bf(s0) | ((unsigned int)f2bf(s1) << 16);
    ((unsigned int*)(xcB + (size_t)m * N_COMP))[c0 >> 1] = pk;
}

// MFMA GEMM: y[m][n] = sum_c xc[m][c] * W[n][c]
// 512 blocks x 256 threads (4 waves). Block owns 16 output columns; wave w
// covers k-slice [w*512, (w+1)*512); LDS reduce at end. Manual 2-deep register
// double-buffer keeps next step's 6 loads in flight during MFMA.
#define KSLICES 4
#define KSL     (N_COMP / KSLICES)   // 512
#define KSTEPS  (KSL / 32)           // 16

__global__ __launch_bounds__(256) void k_gemm(const float* __restrict__ W,
                                              const unsigned short* __restrict__ xcB,
                                              float* __restrict__ y) {
    __shared__ float ys[KSLICES][M_ROWS][16];  // 16 KB
    const int tid  = threadIdx.x;
    const int lane = tid & 63;
    const int w    = __builtin_amdgcn_readfirstlane(tid >> 6);
    const int nr   = lane & 15;
    const int kg   = lane >> 4;
    const int n0   = blockIdx.x * 16;

    const float*          wp = W   + (size_t)(n0 + nr) * N_COMP + w * KSL + kg * 8;
    const unsigned short* ap = xcB + (size_t)nr * N_COMP        + w * KSL + kg * 8;

    f32x4 acc0 = {0.f, 0.f, 0.f, 0.f};
    f32x4 acc1 = {0.f, 0.f, 0.f, 0.f};
    f32x4 acc2 = {0.f, 0.f, 0.f, 0.f};
    f32x4 acc3 = {0.f, 0.f, 0.f, 0.f};

#define LOADW(W0, W1, S) do { int ko_ = (S) * 32;                      \
        (W0) = *(const float4*)(wp + ko_);                             \
        (W1) = *(const float4*)(wp + ko_ + 4); } while (0)
#define LOADA(A0, A1, A2, A3, S) do { int ko_ = (S) * 32;              \
        (A0) = *(const bf16x8*)(ap + ko_);                             \
        (A1) = *(const bf16x8*)(ap + 16 * N_COMP + ko_);               \
        (A2) = *(const bf16x8*)(ap + 32 * N_COMP + ko_);               \
        (A3) = *(const bf16x8*)(ap + 48 * N_COMP + ko_); } while (0)
#define DOMFMA(W0, W1, A0, A1, A2, A3) do { bf16x8 b_;                 \
        b_[0] = (short)f2bf((W0).x); b_[1] = (short)f2bf((W0).y);      \
        b_[2] = (short)f2bf((W0).z); b_[3] = (short)f2bf((W0).w);      \
        b_[4] = (short)f2bf((W1).x); b_[5] = (short)f2bf((W1).y);      \
        b_[6] = (short)f2bf((W1).z); b_[7] = (short)f2bf((W1).w);      \
        acc0 = __builtin_amdgcn_mfma_f32_16x16x32_bf16((A0), b_, acc0, 0, 0, 0); \
        acc1 = __builtin_amdgcn_mfma_f32_16x16x32_bf16((A1), b_, acc1, 0, 0, 0); \
        acc2 = __builtin_amdgcn_mfma_f32_16x16x32_bf16((A2), b_, acc2, 0, 0, 0); \
        acc3 = __builtin_amdgcn_mfma_f32_16x16x32_bf16((A3), b_, acc3, 0, 0, 0); } while (0)

    float4 wa0, wa1, wb0, wb1;
    bf16x8 aa0, aa1, aa2, aa3, ab0, ab1, ab2, ab3;

    LOADW(wa0, wa1, 0);
    LOADA(aa0, aa1, aa2, aa3, 0);
#pragma unroll 1
    for (int s = 0; s < KSTEPS - 2; s += 2) {
        LOADW(wb0, wb1, s + 1);
        LOADA(ab0, ab1, ab2, ab3, s + 1);
        DOMFMA(wa0, wa1, aa0, aa1, aa2, aa3);
        LOADW(wa0, wa1, s + 2);
        LOADA(aa0, aa1, aa2, aa3, s + 2);
        DOMFMA(wb0, wb1, ab0, ab1, ab2, ab3);
    }
    LOADW(wb0, wb1, KSTEPS - 1);
    LOADA(ab0, ab1, ab2, ab3, KSTEPS - 1);
    DOMFMA(wa0, wa1, aa0, aa1, aa2, aa3);
    DOMFMA(wb0, wb1, ab0, ab1, ab2, ab3);

    // C/D layout (m89-verified): col = lane&15, row = (lane>>4)*4 + j
#pragma unroll
    for (int j = 0; j < 4; ++j) {
        ys[w][ 0 + kg * 4 + j][nr] = acc0[j];
        ys[w][16 + kg * 4 + j][nr] = acc1[j];
        ys[w][32 + kg * 4 + j][nr] = acc2[j];
        ys[w][48 + kg * 4 + j][nr] = acc3[j];
    }
    __syncthreads();

    // Reduce k-slices and store: 1024 outputs, 4 per thread
#pragma unroll
    for (int i = 0; i < 4; ++i) {
        int o = tid + 256 * i;
        int m = o >> 4;
        int n = o & 15;
        float s = ys[0][m][n] + ys[1][m][n] + ys[2][m][n] + ys[3][m][n];
        y[(size_t)m * N_OUT + n0 + n] = s;
    }
}

extern "C" void kernel_launch(void* const* d_in, const int* in_sizes, int n_in,
                              void* d_out, int out_size, void* d_ws, size_t ws_size,
                              hipStream_t stream) {
    const float* x = (const float*)d_in[0];
    const float* W = (const float*)d_in[1];
    const int* rn  = (const int*)d_in[2];
    float* y       = (float*)d_out;

    float* partial      = (float*)d_ws;
    unsigned short* xcB = (unsigned short*)((char*)d_ws + 256 * N_COMP * sizeof(float));

    k_part<<<256, 512, 0, stream>>>(x, rn, partial);
    k_pack<<<256, 256, 0, stream>>>(partial, xcB);
    k_gemm<<<N_OUT / 16, 256, 0, stream>>>(W, xcB, y);
}

// Round 6
// 36.243 us; speedup vs baseline: 4.8360x; 1.0028x over previous
//
#include <hip/hip_runtime.h>
#include <hip/hip_bf16.h>

// Problem constants (fixed by setup_inputs):
//   x: (64, 8192) f32   weight: (8192, 2048) f32
//   random_numbers: (4,) int (int32 or int64 storage, values in [1, 2^20))
//   y: (64, 8192) f32
#define K_FULL   8192
#define M_ROWS   64
#define N_OUT    8192
#define N_COMP   2048
#define P_MERS   2147483647

// ws layout:
//   [0, 2MB)        : partial f32 [256][N_COMP]   (b = m*4 + jq)
//   [2MB, 2.25MB)   : xcB bf16 [M_ROWS][N_COMP]   (GEMM A operand)

typedef __attribute__((ext_vector_type(8))) short bf16x8;
typedef __attribute__((ext_vector_type(4))) float f32x4;

// Native f32->bf16 (compiler emits v_cvt_pk_bf16_f32 pairs; RNE)
__device__ __forceinline__ short f2bfs(float f) {
    __hip_bfloat16 h = __float2bfloat16(f);
    return *reinterpret_cast<short*>(&h);
}

__device__ __forceinline__ int hash_col(int j, int rn0, int rn1, int rn2, int rn3) {
    if (rn1 == 0 && rn3 == 0) {
        // int64 storage (JAX x64 on): exact int64 hash.
        // x = r0*j + r1 < 2^33;  x mod (2^31-1) via 2^31 === 1 (mod P).
        unsigned long long xx = (unsigned long long)(unsigned int)rn0 * (unsigned int)j
                              + (unsigned long long)(unsigned int)rn2;
        unsigned long long t = (xx & (unsigned long long)P_MERS) + (xx >> 31);
        if (t >= (unsigned long long)P_MERS) t -= (unsigned long long)P_MERS;
        return (int)(t & (N_COMP - 1));
    } else {
        // int32 storage (JAX x64 off): int32 wraparound + floored mod
        unsigned int t = (unsigned int)rn0 * (unsigned int)j + (unsigned int)rn1;
        int ti = (int)t;
        int m1 = ti % P_MERS;
        if (m1 < 0) m1 += P_MERS;
        return m1 & (N_COMP - 1);
    }
}

// Partial compressed rows: block b = (m, jq). Accumulate x[m][jq*2048 .. +2048)
// into LDS row by hashed column, then write partial[b][*]. No global atomics.
__global__ __launch_bounds__(512) void k_part(const float* __restrict__ x,
                                              const int* __restrict__ rn,
                                              float* __restrict__ partial) {
    __shared__ float row[N_COMP];
    const int b = blockIdx.x;
    const int m = b >> 2;
    const int jq = b & 3;
    const int tid = threadIdx.x;
#pragma unroll
    for (int i = 0; i < 4; ++i) row[tid + 512 * i] = 0.0f;
    const int rn0 = rn[0], rn1 = rn[1], rn2 = rn[2], rn3 = rn[3];
    __syncthreads();

    const int j0 = jq * 2048 + tid * 4;
    float4 v = *(const float4*)(x + (size_t)m * K_FULL + j0);
    atomicAdd(&row[hash_col(j0 + 0, rn0, rn1, rn2, rn3)], v.x);
    atomicAdd(&row[hash_col(j0 + 1, rn0, rn1, rn2, rn3)], v.y);
    atomicAdd(&row[hash_col(j0 + 2, rn0, rn1, rn2, rn3)], v.z);
    atomicAdd(&row[hash_col(j0 + 3, rn0, rn1, rn2, rn3)], v.w);
    __syncthreads();

    float4 o = { row[4 * tid], row[4 * tid + 1], row[4 * tid + 2], row[4 * tid + 3] };
    *(float4*)(partial + (size_t)b * N_COMP + 4 * tid) = o;
}

// Reduce 4 partials per (m, c) and pack to bf16 xcB[m][c].
__global__ __launch_bounds__(256) void k_pack(const float* __restrict__ partial,
                                              unsigned short* __restrict__ xcB) {
    const int b = blockIdx.x;          // 256 blocks
    const int m = b >> 2;
    const int c0 = (b & 3) * 512 + threadIdx.x * 2;
    const float* p = partial + (size_t)m * 4 * N_COMP + c0;
    float s0 = p[0] + p[N_COMP] + p[2 * N_COMP] + p[3 * N_COMP];
    float s1 = p[1] + p[N_COMP + 1] + p[2 * N_COMP + 1] + p[3 * N_COMP + 1];
    unsigned int pk = (unsigned int)(unsigned short)f2bfs(s0)
                    | ((unsigned int)(unsigned short)f2bfs(s1) << 16);
    ((unsigned int*)(xcB + (size_t)m * N_COMP))[c0 >> 1] = pk;
}

// MFMA GEMM: y[m][n] = sum_c xc[m][c] * W[n][c]
// 512 blocks x 512 threads (8 waves). Block owns 16 output columns; wave w
// covers k-slice [w*256, (w+1)*256); LDS reduce at end. Manual 2-deep register
// double-buffer (unroll 1) keeps next step's 6 loads in flight during MFMA.
#define KSLICES 8
#define KSL     (N_COMP / KSLICES)   // 256
#define KSTEPS  (KSL / 32)           // 8

__global__ __launch_bounds__(512) void k_gemm(const float* __restrict__ W,
                                              const unsigned short* __restrict__ xcB,
                                              float* __restrict__ y) {
    __shared__ float ys[KSLICES][M_ROWS][16];  // 32 KB
    const int tid  = threadIdx.x;
    const int lane = tid & 63;
    const int w    = __builtin_amdgcn_readfirstlane(tid >> 6);
    const int nr   = lane & 15;
    const int kg   = lane >> 4;
    const int n0   = blockIdx.x * 16;

    const float*          wp = W   + (size_t)(n0 + nr) * N_COMP + w * KSL + kg * 8;
    const unsigned short* ap = xcB + (size_t)nr * N_COMP        + w * KSL + kg * 8;

    f32x4 acc0 = {0.f, 0.f, 0.f, 0.f};
    f32x4 acc1 = {0.f, 0.f, 0.f, 0.f};
    f32x4 acc2 = {0.f, 0.f, 0.f, 0.f};
    f32x4 acc3 = {0.f, 0.f, 0.f, 0.f};

#define LOADW(W0, W1, S) do { int ko_ = (S) * 32;                      \
        (W0) = *(const float4*)(wp + ko_);                             \
        (W1) = *(const float4*)(wp + ko_ + 4); } while (0)
#define LOADA(A0, A1, A2, A3, S) do { int ko_ = (S) * 32;              \
        (A0) = *(const bf16x8*)(ap + ko_);                             \
        (A1) = *(const bf16x8*)(ap + 16 * N_COMP + ko_);               \
        (A2) = *(const bf16x8*)(ap + 32 * N_COMP + ko_);               \
        (A3) = *(const bf16x8*)(ap + 48 * N_COMP + ko_); } while (0)
#define DOMFMA(W0, W1, A0, A1, A2, A3) do { bf16x8 b_;                 \
        b_[0] = f2bfs((W0).x); b_[1] = f2bfs((W0).y);                  \
        b_[2] = f2bfs((W0).z); b_[3] = f2bfs((W0).w);                  \
        b_[4] = f2bfs((W1).x); b_[5] = f2bfs((W1).y);                  \
        b_[6] = f2bfs((W1).z); b_[7] = f2bfs((W1).w);                  \
        acc0 = __builtin_amdgcn_mfma_f32_16x16x32_bf16((A0), b_, acc0, 0, 0, 0); \
        acc1 = __builtin_amdgcn_mfma_f32_16x16x32_bf16((A1), b_, acc1, 0, 0, 0); \
        acc2 = __builtin_amdgcn_mfma_f32_16x16x32_bf16((A2), b_, acc2, 0, 0, 0); \
        acc3 = __builtin_amdgcn_mfma_f32_16x16x32_bf16((A3), b_, acc3, 0, 0, 0); } while (0)

    float4 wa0, wa1, wb0, wb1;
    bf16x8 aa0, aa1, aa2, aa3, ab0, ab1, ab2, ab3;

    LOADW(wa0, wa1, 0);
    LOADA(aa0, aa1, aa2, aa3, 0);
#pragma unroll 1
    for (int s = 0; s < KSTEPS - 2; s += 2) {
        LOADW(wb0, wb1, s + 1);
        LOADA(ab0, ab1, ab2, ab3, s + 1);
        DOMFMA(wa0, wa1, aa0, aa1, aa2, aa3);
        LOADW(wa0, wa1, s + 2);
        LOADA(aa0, aa1, aa2, aa3, s + 2);
        DOMFMA(wb0, wb1, ab0, ab1, ab2, ab3);
    }
    LOADW(wb0, wb1, KSTEPS - 1);
    LOADA(ab0, ab1, ab2, ab3, KSTEPS - 1);
    DOMFMA(wa0, wa1, aa0, aa1, aa2, aa3);
    DOMFMA(wb0, wb1, ab0, ab1, ab2, ab3);

    // C/D layout (m89-verified): col = lane&15, row = (lane>>4)*4 + j
#pragma unroll
    for (int j = 0; j < 4; ++j) {
        ys[w][ 0 + kg * 4 + j][nr] = acc0[j];
        ys[w][16 + kg * 4 + j][nr] = acc1[j];
        ys[w][32 + kg * 4 + j][nr] = acc2[j];
        ys[w][48 + kg * 4 + j][nr] = acc3[j];
    }
    __syncthreads();

    // Reduce k-slices and store: 1024 outputs, 2 per thread
#pragma unroll
    for (int i = 0; i < 2; ++i) {
        int o = tid + 512 * i;
        int m = o >> 4;
        int n = o & 15;
        float s = 0.f;
#pragma unroll
        for (int q = 0; q < KSLICES; ++q) s += ys[q][m][n];
        y[(size_t)m * N_OUT + n0 + n] = s;
    }
}

extern "C" void kernel_launch(void* const* d_in, const int* in_sizes, int n_in,
                              void* d_out, int out_size, void* d_ws, size_t ws_size,
                              hipStream_t stream) {
    const float* x = (const float*)d_in[0];
    const float* W = (const float*)d_in[1];
    const int* rn  = (const int*)d_in[2];
    float* y       = (float*)d_out;

    float* partial      = (float*)d_ws;
    unsigned short* xcB = (unsigned short*)((char*)d_ws + 256 * N_COMP * sizeof(float));

    k_part<<<256, 512, 0, stream>>>(x, rn, partial);
    k_pack<<<256, 256, 0, stream>>>(partial, xcB);
    k_gemm<<<N_OUT / 16, 512, 0, stream>>>(W, xcB, y);
}